// Round 3
// baseline (1009.431 us; speedup 1.0000x reference)
//
#include <hip/hip_runtime.h>

#define LL 8
#define BB 32
#define SS 512
#define DD 256
#define EE 2048
#define LED (LL*DD*EE)   // 4194304
#define LE  (LL*EE)      // 16384
#define NROWS (BB*LL*SS) // 131072
#define NSEG 32          // per-m staged segments: 16 ks x {hi,lo}

typedef __bf16 bf16x8 __attribute__((ext_vector_type(8)));
typedef float  f32x16 __attribute__((ext_vector_type(16)));

// ---------------------------------------------------------------------------
// Kernel 1: transpose embed (L,D,E) -> embed_t (L,E,D) and accumulate norms
// ---------------------------------------------------------------------------
__global__ void transpose_norms_kernel(const float* __restrict__ embed,
                                       float* __restrict__ embed_t,
                                       float* __restrict__ norms) {
    __shared__ float tile[32][33];
    const int l  = blockIdx.z;
    const int d0 = blockIdx.y * 32;
    const int e0 = blockIdx.x * 32;
    const int tx = threadIdx.x, ty = threadIdx.y;

    float v = embed[((size_t)l*DD + d0 + ty)*EE + e0 + tx];
    tile[ty][tx] = v;
    __syncthreads();
    embed_t[((size_t)l*EE + e0 + ty)*DD + d0 + tx] = tile[tx][ty];
    __syncthreads();
    tile[ty][tx] = v * v;
    __syncthreads();
    if (ty == 0) {
        float s = 0.f;
        #pragma unroll
        for (int i = 0; i < 32; ++i) s += tile[i][tx];
        atomicAdd(&norms[l*EE + e0 + tx], s);
    }
}

// ---------------------------------------------------------------------------
// Kernel 1b: embed -> 32-segment MFMA fragment layout per (l,m):
//   seg s: half = s>>4 (0: ks 0..7, 1: ks 8..15), k = (s&15)>>1, lo = s&1
// Each segment = 512 bf16 (lane*8 + j).
// ---------------------------------------------------------------------------
__global__ void prep_embed_frag(const float* __restrict__ embed,
                                __bf16* __restrict__ frag) {
    const int bid  = blockIdx.x;          // (l*64 + m)*32 + s
    const int s    = bid & 31;
    const int m    = (bid >> 5) & 63;
    const int l    = bid >> 11;
    const int lane = threadIdx.x;
    const int e    = m*32 + (lane & 31);
    const int ks   = ((s >> 4) << 3) + ((s & 15) >> 1);
    const bool lo  = s & 1;
    const int kbase = ks*16 + (lane >> 5)*8;

    bf16x8 v;
    #pragma unroll
    for (int j = 0; j < 8; ++j) {
        float val = embed[((size_t)l*DD + kbase + j)*EE + e];
        __bf16 h = (__bf16)val;
        v[j] = lo ? (__bf16)(val - (float)h) : h;
    }
    *(bf16x8*)(frag + (size_t)bid*512 + lane*8) = v;
}

// ---------------------------------------------------------------------------
// Kernel 2: MFMA argmin. Simple r1-style schedule (compiler-scheduled), but:
//  - 2-slot LDS ring at half-m granularity (16 KB/slot) + 8 KB norm table
//    => 40 KB LDS => 3 blocks/CU (12 waves/CU, was 8)
//  - norm folded exactly via fmaf in the argmax (no norm MFMA k-step)
//  - 1 accumulator chain => ~164 total regs, __launch_bounds__(256,3)
//  + fused counts histogram + fused q-gather/out/diff.
// ---------------------------------------------------------------------------
__global__ __launch_bounds__(256, 3)
void argmin_mfma(const float* __restrict__ x,
                 const __bf16* __restrict__ frag,
                 const float* __restrict__ embed_t,
                 const float* __restrict__ norms,
                 int* __restrict__ ids_out,
                 int* __restrict__ counts_i,
                 float* __restrict__ out,
                 float* __restrict__ diff_acc) {
    __shared__ __bf16 slots[2][16*512];   // 32 KB ring (half-m units)
    __shared__ float  normbuf[EE];        // 8 KB per-l norms

    const int tid  = threadIdx.x;
    const int wave = tid >> 6, lane = tid & 63;
    const int l    = blockIdx.x & 7;
    const int rb   = blockIdx.x >> 3;
    const int idx  = rb*4 + wave;
    const int b    = idx >> 4, st = idx & 15;
    const int rowtile = (b*LL + l)*16 + st;

    // stage norms for this l into LDS (8 x 1KB, linear)
    {
        const float* np = norms + l*EE;
        for (int i = wave; i < 8; i += 4) {
            __builtin_amdgcn_global_load_lds(
                (const __attribute__((address_space(1))) void*)(np + i*256 + lane*4),
                (__attribute__((address_space(3))) void*)(normbuf + i*256), 16, 0, 0);
        }
    }

    // x -> B fragments (hi/lo bf16 split)
    bf16x8 bh[16], bl[16];
    {
        const float* xr = x + (size_t)(rowtile*32 + (lane & 31))*DD + (lane >> 5)*8;
        #pragma unroll
        for (int ks = 0; ks < 16; ++ks) {
            float4 v0 = *(const float4*)(xr + ks*16);
            float4 v1 = *(const float4*)(xr + ks*16 + 4);
            float f[8] = {v0.x, v0.y, v0.z, v0.w, v1.x, v1.y, v1.z, v1.w};
            #pragma unroll
            for (int j = 0; j < 8; ++j) {
                __bf16 h = (__bf16)f[j];
                bh[ks][j] = h;
                bl[ks][j] = (__bf16)(f[j] - (float)h);
            }
        }
    }

    const __bf16* fl = frag + (size_t)l*64*NSEG*512;

    // stage half-m unit (16 segs) into slot; 4 global_load_lds per wave
    auto stage_half = [&](int m, int half, int slot) {
        const __bf16* src = fl + ((size_t)m*NSEG + half*16)*512 + lane*8;
        __bf16* dst = &slots[slot][0];
        for (int i = wave; i < 16; i += 4) {
            __builtin_amdgcn_global_load_lds(
                (const __attribute__((address_space(1))) void*)(src + i*512),
                (__attribute__((address_space(3))) void*)(dst + i*512), 16, 0, 0);
        }
    };

    float maxv = -3.4e38f;
    int   maxi = 0;

    stage_half(0, 0, 0);
    __syncthreads();   // also covers normbuf + nothing reads x-frags cross-wave

    #pragma unroll 1
    for (int t = 0; t < 64; ++t) {
        stage_half(t, 1, 1);

        f32x16 acc;
        #pragma unroll
        for (int i = 0; i < 16; ++i) acc[i] = 0.0f;

        // ks 0..7 from slot 0
        #pragma unroll
        for (int k = 0; k < 8; ++k) {
            bf16x8 ah = *(const bf16x8*)(&slots[0][0] + (2*k    )*512 + lane*8);
            bf16x8 al = *(const bf16x8*)(&slots[0][0] + (2*k + 1)*512 + lane*8);
            acc = __builtin_amdgcn_mfma_f32_32x32x16_bf16(ah, bh[k], acc, 0, 0, 0);
            acc = __builtin_amdgcn_mfma_f32_32x32x16_bf16(ah, bl[k], acc, 0, 0, 0);
            acc = __builtin_amdgcn_mfma_f32_32x32x16_bf16(al, bh[k], acc, 0, 0, 0);
        }
        __syncthreads();   // slot1 staged; slot0 free

        if (t < 63) stage_half(t + 1, 0, 0);

        // ks 8..15 from slot 1
        #pragma unroll
        for (int k = 0; k < 8; ++k) {
            bf16x8 ah = *(const bf16x8*)(&slots[1][0] + (2*k    )*512 + lane*8);
            bf16x8 al = *(const bf16x8*)(&slots[1][0] + (2*k + 1)*512 + lane*8);
            acc = __builtin_amdgcn_mfma_f32_32x32x16_bf16(ah, bh[8+k], acc, 0, 0, 0);
            acc = __builtin_amdgcn_mfma_f32_32x32x16_bf16(ah, bl[8+k], acc, 0, 0, 0);
            acc = __builtin_amdgcn_mfma_f32_32x32x16_bf16(al, bh[8+k], acc, 0, 0, 0);
        }

        // argmax with exact norm fold: v = acc - 0.5*||e||^2
        const int ebase = t*32 + 4*(lane >> 5);
        #pragma unroll
        for (int j = 0; j < 4; ++j) {
            float4 nv = *(const float4*)(normbuf + t*32 + 8*j + 4*(lane >> 5));
            #pragma unroll
            for (int rr = 0; rr < 4; ++rr) {
                float v = fmaf(-0.5f, (&nv.x)[rr], acc[4*j + rr]);
                int e = ebase + rr + 8*j;
                // e visited in ascending order per lane -> strict > keeps smallest e
                if (v > maxv) { maxv = v; maxi = e; }
            }
        }
        __syncthreads();   // slot0 staged for t+1; slot1 free
    }

    float ov = __shfl_xor(maxv, 32, 64);
    int   oi = __shfl_xor(maxi, 32, 64);
    if (ov > maxv || (ov == maxv && oi < maxi)) { maxv = ov; maxi = oi; }
    if (lane < 32) {
        ids_out[(size_t)rowtile*32 + lane] = maxi;
        atomicAdd(&counts_i[l*EE + maxi], 1);
    }

    // ---- fused gather q -> out (+ diff partial for l == L-1) ----
    const float4* et4  = (const float4*)embed_t;
    const float4* x4   = (const float4*)x;
    float4*       out4 = (float4*)out;
    float sq = 0.f;
    #pragma unroll 4
    for (int r = 0; r < 32; ++r) {
        int id = __shfl(maxi, r);   // all 64 lanes hold row r's result after combine
        float4 qv = et4[((size_t)l*EE + id)*64 + lane];
        size_t o = ((size_t)rowtile*32 + r)*64 + lane;
        out4[o] = qv;
        if (l == LL - 1) {
            float4 xv = x4[o];
            float dx = qv.x - xv.x, dy = qv.y - xv.y, dz = qv.z - xv.z, dw = qv.w - xv.w;
            sq += dx*dx + dy*dy + dz*dz + dw*dw;
        }
    }
    if (l == LL - 1) {
        #pragma unroll
        for (int off = 32; off; off >>= 1) sq += __shfl_down(sq, off);
        if (lane == 0) atomicAdd(diff_acc, sq);
    }
}

// ---------------------------------------------------------------------------
// Kernel 2b: per-l exclusive scan of counts -> bin_start, cursor
//            + fused new_cluster_size & per-l sum n
// ---------------------------------------------------------------------------
__global__ __launch_bounds__(256)
void scan_kernel(const int* __restrict__ counts_i,
                 const float* __restrict__ cs_in,
                 int* __restrict__ bin_start,
                 int* __restrict__ cursor,
                 float* __restrict__ ncs_out,
                 float* __restrict__ n_out) {
    __shared__ int part[256];
    __shared__ float red[4];
    const int l = blockIdx.x, tid = threadIdx.x;
    const int base = l*EE + tid*8;
    int local[8], tsum = 0;
    float fsum = 0.f;
    #pragma unroll
    for (int j = 0; j < 8; ++j) {
        local[j] = counts_i[base + j];
        tsum += local[j];
        float v = 0.999f*cs_in[base + j] + 0.001f*(float)local[j];
        ncs_out[base + j] = v;
        fsum += v;
    }
    part[tid] = tsum;
    __syncthreads();
    for (int off = 1; off < 256; off <<= 1) {
        int v = (tid >= off) ? part[tid - off] : 0;
        __syncthreads();
        part[tid] += v;
        __syncthreads();
    }
    int run = part[tid] - tsum;
    #pragma unroll
    for (int j = 0; j < 8; ++j) {
        bin_start[base + j] = run;
        cursor[base + j]    = run;
        run += local[j];
    }
    #pragma unroll
    for (int off = 32; off; off >>= 1) fsum += __shfl_down(fsum, off);
    if ((tid & 63) == 0) red[tid >> 6] = fsum;
    __syncthreads();
    if (tid == 0) n_out[l] = red[0] + red[1] + red[2] + red[3];
}

// ---------------------------------------------------------------------------
// Kernel 2c: scatter row indices into per-l sorted order
// ---------------------------------------------------------------------------
__global__ __launch_bounds__(256)
void scatter_idx_kernel(const int* __restrict__ ids,
                        int* __restrict__ cursor,
                        int* __restrict__ sorted_rows) {
    const int r = blockIdx.x*256 + threadIdx.x;
    const int l = (r >> 9) & 7;
    const int e = ids[r];
    int pos = atomicAdd(&cursor[l*EE + e], 1);
    sorted_rows[l*(NROWS/LL) + pos] = r;
}

// ---------------------------------------------------------------------------
// Kernel 2d: segmented sum — one block per (l,e), threads = d
// ---------------------------------------------------------------------------
__global__ __launch_bounds__(256)
void segsum_kernel(const float* __restrict__ x,
                   const int* __restrict__ sorted_rows,
                   const int* __restrict__ bin_start,
                   const int* __restrict__ counts_i,
                   float* __restrict__ embed_sum) {
    const int bid = blockIdx.x;
    const int l   = bid >> 11;
    const int e   = bid & 2047;
    const int tid = threadIdx.x;
    const int start = bin_start[l*EE + e];
    const int cnt   = counts_i[l*EE + e];
    const int* rows = sorted_rows + l*(NROWS/LL);

    float acc = 0.f;
    int i = 0;
    for (; i + 1 < cnt; i += 2) {
        int r0 = rows[start + i], r1 = rows[start + i + 1];
        acc += x[(size_t)r0*DD + tid] + x[(size_t)r1*DD + tid];
    }
    if (i < cnt) acc += x[(size_t)rows[start + i]*DD + tid];
    embed_sum[((size_t)l*EE + e)*DD + tid] = acc;
}

// ---------------------------------------------------------------------------
// Kernel 5: new_embed_avg + new_embed
// ---------------------------------------------------------------------------
__global__ void finalize_embed_kernel(const float* __restrict__ embed_avg,
                                      const float* __restrict__ embed_sum,
                                      const float* __restrict__ ncs,
                                      const float* __restrict__ n,
                                      float* __restrict__ nea_out,
                                      float* __restrict__ ne_out) {
    __shared__ float tile[32][33];
    const int l  = blockIdx.z;
    const int d0 = blockIdx.y * 32;
    const int e0 = blockIdx.x * 32;
    const int tx = threadIdx.x, ty = threadIdx.y;

    tile[ty][tx] = embed_sum[((size_t)l*EE + e0 + ty)*DD + d0 + tx];
    __syncthreads();
    const size_t idx = ((size_t)l*DD + d0 + ty)*EE + e0 + tx;
    float nea = 0.999f*embed_avg[idx] + 0.001f*tile[tx][ty];
    nea_out[idx] = nea;
    float nl = n[l];
    float c  = ncs[l*EE + e0 + tx];
    float cs = (c + 1e-5f) / (nl + 0.02048f) * nl;
    ne_out[idx] = nea / cs;
}

// ---------------------------------------------------------------------------
// Kernel 6: diff scale
// ---------------------------------------------------------------------------
__global__ void diff_scale_kernel(const float* __restrict__ diff_acc,
                                  float* __restrict__ diff_out) {
    *diff_out = (*diff_acc / (float)(BB*SS*DD)) * 0.25f;
}

// ---------------------------------------------------------------------------
extern "C" void kernel_launch(void* const* d_in, const int* in_sizes, int n_in,
                              void* d_out, int out_size, void* d_ws, size_t ws_size,
                              hipStream_t stream) {
    const float* x            = (const float*)d_in[0];
    const float* embed        = (const float*)d_in[1];
    const float* cluster_size = (const float*)d_in[2];
    const float* embed_avg    = (const float*)d_in[3];

    float* out      = (float*)d_out;
    float* diff_out = out + 33554432;
    int*   ids_out  = (int*)(out + 33554433);
    float* ne_out   = out + 33685505;
    float* ncs_out  = out + 37879809;
    float* nea_out  = out + 37896193;

    float* ws        = (float*)d_ws;
    float* embed_t   = ws;                          // LED floats
    float* embed_sum = ws + LED;                    // LED floats (fully written by segsum)
    int*   counts_i  = (int*)(ws + 2*(size_t)LED);  // LE ints   (zeroed)
    float* norms     = ws + 2*(size_t)LED + LE;     // LE floats (zeroed)
    float* diff_acc  = norms + LE;                  // 1 float   (zeroed)
    float* n_ws      = diff_acc + 1;                // LL floats
    int*   bin_start = (int*)(n_ws + LL);           // LE ints
    int*   cursor    = bin_start + LE;              // LE ints
    int*   sorted_rows = cursor + LE;               // NROWS ints
    __bf16* embfrag  = (__bf16*)(sorted_rows + NROWS + 16);  // LL*64*32*512 bf16 = 16 MB

    // zero: counts_i, norms, diff_acc (contiguous)
    hipMemsetAsync(counts_i, 0, (size_t)(2*LE + 1) * sizeof(float), stream);

    transpose_norms_kernel<<<dim3(EE/32, DD/32, LL), dim3(32, 32), 0, stream>>>(
        embed, embed_t, norms);

    prep_embed_frag<<<LL*64*NSEG, 64, 0, stream>>>(embed, embfrag);

    argmin_mfma<<<1024, 256, 0, stream>>>(x, embfrag, embed_t, norms, ids_out,
                                          counts_i, out, diff_acc);

    scan_kernel<<<LL, 256, 0, stream>>>(counts_i, cluster_size, bin_start, cursor,
                                        ncs_out, n_ws);

    scatter_idx_kernel<<<NROWS/256, 256, 0, stream>>>(ids_out, cursor, sorted_rows);

    segsum_kernel<<<LE, 256, 0, stream>>>(x, sorted_rows, bin_start, counts_i, embed_sum);

    finalize_embed_kernel<<<dim3(EE/32, DD/32, LL), dim3(32, 32), 0, stream>>>(
        embed_avg, embed_sum, ncs_out, n_ws, nea_out, ne_out);

    diff_scale_kernel<<<1, 1, 0, stream>>>(diff_acc, diff_out);
}

// Round 4
// 959.742 us; speedup vs baseline: 1.0518x; 1.0518x over previous
//
#include <hip/hip_runtime.h>

#define LL 8
#define BB 32
#define SS 512
#define DD 256
#define EE 2048
#define LED (LL*DD*EE)   // 4194304
#define LE  (LL*EE)      // 16384
#define NROWS (BB*LL*SS) // 131072
#define NSEG 32          // per-m staged segments: 16 ks x {hi,lo} interleaved

typedef __bf16 bf16x8 __attribute__((ext_vector_type(8)));
typedef float  f32x16 __attribute__((ext_vector_type(16)));

// ---------------------------------------------------------------------------
// Kernel 1 (merged): embed -> embed_t (transpose), norms (atomic partial),
// and MFMA A-fragment bf16 hi/lo segments — embed read exactly once.
// Per block: (l, d0=32-tile, e0=32-tile) => m = e0/32, ks = d0/16 .. +1.
// Frag layout per (l,m): seg s = 2*ks + (lo?1:0); seg elem (lane*8+j) holds
// d = ks*16 + (lane>>5)*8 + j, e = m*32 + (lane&31).
// ---------------------------------------------------------------------------
__global__ void prep_transpose_kernel(const float* __restrict__ embed,
                                      float* __restrict__ embed_t,
                                      float* __restrict__ norms,
                                      __bf16* __restrict__ frag) {
    __shared__ float tile[32][33];
    const int l  = blockIdx.z;
    const int d0 = blockIdx.y * 32;
    const int e0 = blockIdx.x * 32;
    const int tx = threadIdx.x, ty = threadIdx.y;

    float v = embed[((size_t)l*DD + d0 + ty)*EE + e0 + tx];
    tile[ty][tx] = v;
    __syncthreads();

    // transpose write
    embed_t[((size_t)l*EE + e0 + ty)*DD + d0 + tx] = tile[tx][ty];

    // frag hi/lo segments (coalesced: consecutive threads -> consecutive pos)
    const int t    = ty*32 + tx;
    const int ksl  = t >> 9;          // which of the 2 ks in this d-tile
    const int pos  = t & 511;         // position within segment
    const int lane = pos >> 3, j = pos & 7;
    const int klocal = (lane >> 5)*8 + j;
    const int e_loc  = lane & 31;
    float val = tile[ksl*16 + klocal][e_loc];
    __bf16 h = (__bf16)val;
    const int m  = blockIdx.x;
    const int ks = (d0 >> 4) + ksl;
    size_t segbase = (((size_t)(l*64 + m))*NSEG + 2*ks)*512 + pos;
    frag[segbase]       = h;
    frag[segbase + 512] = (__bf16)(val - (float)h);

    // norms partial
    if (ty == 0) {
        float s = 0.f;
        #pragma unroll
        for (int i = 0; i < 32; ++i) s += tile[i][tx]*tile[i][tx];
        atomicAdd(&norms[l*EE + e0 + tx], s);
    }
}

// ---------------------------------------------------------------------------
// Kernel 2: MFMA argmin — r1-proven schedule (full-m double-buffer, one
// barrier per m) + T5 setprio around the compute cluster (cross-block
// arbitration: 2 independent-phase blocks/CU) + exact fp32 norm fold.
// + fused counts histogram + fused q-gather/out/diff.
// ---------------------------------------------------------------------------
__global__ __launch_bounds__(256, 2)
void argmin_mfma(const float* __restrict__ x,
                 const __bf16* __restrict__ frag,
                 const float* __restrict__ embed_t,
                 const float* __restrict__ norms,
                 int* __restrict__ ids_out,
                 int* __restrict__ counts_i,
                 float* __restrict__ out,
                 float* __restrict__ diff_acc) {
    __shared__ __bf16 slots[2][NSEG*512];  // 64 KB double buffer (full m)
    __shared__ float  normbuf[EE];         // 8 KB per-l norms

    const int tid  = threadIdx.x;
    const int wave = tid >> 6, lane = tid & 63;
    const int l    = blockIdx.x & 7;
    const int rb   = blockIdx.x >> 3;
    const int idx  = rb*4 + wave;
    const int b    = idx >> 4, st = idx & 15;
    const int rowtile = (b*LL + l)*16 + st;

    // stage per-l norms into LDS (8 x 1KB, linear)
    {
        const float* np = norms + l*EE;
        for (int i = wave; i < 8; i += 4) {
            __builtin_amdgcn_global_load_lds(
                (const __attribute__((address_space(1))) void*)(np + i*256 + lane*4),
                (__attribute__((address_space(3))) void*)(normbuf + i*256), 16, 0, 0);
        }
    }

    // x -> B fragments (hi/lo bf16 split)
    bf16x8 bh[16], bl[16];
    {
        const float* xr = x + (size_t)(rowtile*32 + (lane & 31))*DD + (lane >> 5)*8;
        #pragma unroll
        for (int ks = 0; ks < 16; ++ks) {
            float4 v0 = *(const float4*)(xr + ks*16);
            float4 v1 = *(const float4*)(xr + ks*16 + 4);
            float f[8] = {v0.x, v0.y, v0.z, v0.w, v1.x, v1.y, v1.z, v1.w};
            #pragma unroll
            for (int j = 0; j < 8; ++j) {
                __bf16 h = (__bf16)f[j];
                bh[ks][j] = h;
                bl[ks][j] = (__bf16)(f[j] - (float)h);
            }
        }
    }

    const __bf16* fl = frag + (size_t)l*64*NSEG*512;

    // stage full m (32 segs); 8 global_load_lds per wave (even split)
    auto stage = [&](int m, int buf) {
        const __bf16* src = fl + (size_t)m*NSEG*512 + lane*8;
        __bf16* dst = &slots[buf][0];
        for (int i = wave; i < NSEG; i += 4) {
            __builtin_amdgcn_global_load_lds(
                (const __attribute__((address_space(1))) void*)(src + i*512),
                (__attribute__((address_space(3))) void*)(dst + i*512), 16, 0, 0);
        }
    };

    float maxv = -3.4e38f;
    int   maxi = 0;

    stage(0, 0);
    __syncthreads();   // also covers normbuf

    #pragma unroll 1
    for (int m = 0; m < 64; ++m) {
        const int buf = m & 1;
        if (m < 63) stage(m + 1, buf ^ 1);

        f32x16 a0, a1, a2;
        #pragma unroll
        for (int i = 0; i < 16; ++i) { a0[i] = 0.0f; a1[i] = 0.0f; a2[i] = 0.0f; }

        const __bf16* sA = &slots[buf][0];
        __builtin_amdgcn_s_setprio(1);
        #pragma unroll
        for (int k = 0; k < 16; ++k) {
            bf16x8 ah = *(const bf16x8*)(sA + (2*k    )*512 + lane*8);
            bf16x8 al = *(const bf16x8*)(sA + (2*k + 1)*512 + lane*8);
            a0 = __builtin_amdgcn_mfma_f32_32x32x16_bf16(ah, bh[k], a0, 0, 0, 0);
            a1 = __builtin_amdgcn_mfma_f32_32x32x16_bf16(ah, bl[k], a1, 0, 0, 0);
            a2 = __builtin_amdgcn_mfma_f32_32x32x16_bf16(al, bh[k], a2, 0, 0, 0);
        }
        __builtin_amdgcn_s_setprio(0);

        // argmax with exact fp32 norm fold: v = acc - 0.5*||e||^2
        const int ebase = m*32 + 4*(lane >> 5);
        #pragma unroll
        for (int j = 0; j < 4; ++j) {
            float4 nv = *(const float4*)(normbuf + m*32 + 8*j + 4*(lane >> 5));
            #pragma unroll
            for (int rr = 0; rr < 4; ++rr) {
                float v = a0[4*j + rr] + a1[4*j + rr] + a2[4*j + rr];
                v = fmaf(-0.5f, (&nv.x)[rr], v);
                int e = ebase + rr + 8*j;
                // e visited in ascending order per lane -> strict > keeps smallest e
                if (v > maxv) { maxv = v; maxi = e; }
            }
        }
        __syncthreads();   // next buffer staged; both halves done reading
    }

    float ov = __shfl_xor(maxv, 32, 64);
    int   oi = __shfl_xor(maxi, 32, 64);
    if (ov > maxv || (ov == maxv && oi < maxi)) { maxv = ov; maxi = oi; }
    if (lane < 32) {
        ids_out[(size_t)rowtile*32 + lane] = maxi;
        atomicAdd(&counts_i[l*EE + maxi], 1);
    }

    // ---- fused gather q -> out (+ diff partial for l == L-1) ----
    const float4* et4  = (const float4*)embed_t;
    const float4* x4   = (const float4*)x;
    float4*       out4 = (float4*)out;
    float sq = 0.f;
    #pragma unroll 4
    for (int r = 0; r < 32; ++r) {
        int id = __shfl(maxi, r);   // all 64 lanes hold row r's result after combine
        float4 qv = et4[((size_t)l*EE + id)*64 + lane];
        size_t o = ((size_t)rowtile*32 + r)*64 + lane;
        out4[o] = qv;
        if (l == LL - 1) {
            float4 xv = x4[o];
            float dx = qv.x - xv.x, dy = qv.y - xv.y, dz = qv.z - xv.z, dw = qv.w - xv.w;
            sq += dx*dx + dy*dy + dz*dz + dw*dw;
        }
    }
    if (l == LL - 1) {
        #pragma unroll
        for (int off = 32; off; off >>= 1) sq += __shfl_down(sq, off);
        if (lane == 0) atomicAdd(diff_acc, sq);
    }
}

// ---------------------------------------------------------------------------
// Kernel 2b: per-l exclusive scan of counts -> bin_start, cursor
//            + fused new_cluster_size & per-l sum n
// ---------------------------------------------------------------------------
__global__ __launch_bounds__(256)
void scan_kernel(const int* __restrict__ counts_i,
                 const float* __restrict__ cs_in,
                 int* __restrict__ bin_start,
                 int* __restrict__ cursor,
                 float* __restrict__ ncs_out,
                 float* __restrict__ n_out) {
    __shared__ int part[256];
    __shared__ float red[4];
    const int l = blockIdx.x, tid = threadIdx.x;
    const int base = l*EE + tid*8;
    int local[8], tsum = 0;
    float fsum = 0.f;
    #pragma unroll
    for (int j = 0; j < 8; ++j) {
        local[j] = counts_i[base + j];
        tsum += local[j];
        float v = 0.999f*cs_in[base + j] + 0.001f*(float)local[j];
        ncs_out[base + j] = v;
        fsum += v;
    }
    part[tid] = tsum;
    __syncthreads();
    for (int off = 1; off < 256; off <<= 1) {
        int v = (tid >= off) ? part[tid - off] : 0;
        __syncthreads();
        part[tid] += v;
        __syncthreads();
    }
    int run = part[tid] - tsum;
    #pragma unroll
    for (int j = 0; j < 8; ++j) {
        bin_start[base + j] = run;
        cursor[base + j]    = run;
        run += local[j];
    }
    #pragma unroll
    for (int off = 32; off; off >>= 1) fsum += __shfl_down(fsum, off);
    if ((tid & 63) == 0) red[tid >> 6] = fsum;
    __syncthreads();
    if (tid == 0) n_out[l] = red[0] + red[1] + red[2] + red[3];
}

// ---------------------------------------------------------------------------
// Kernel 2c: scatter row indices into per-l sorted order
// ---------------------------------------------------------------------------
__global__ __launch_bounds__(256)
void scatter_idx_kernel(const int* __restrict__ ids,
                        int* __restrict__ cursor,
                        int* __restrict__ sorted_rows) {
    const int r = blockIdx.x*256 + threadIdx.x;
    const int l = (r >> 9) & 7;
    const int e = ids[r];
    int pos = atomicAdd(&cursor[l*EE + e], 1);
    sorted_rows[l*(NROWS/LL) + pos] = r;
}

// ---------------------------------------------------------------------------
// Kernel 2d: segmented sum — one block per (l,e), threads = d
// ---------------------------------------------------------------------------
__global__ __launch_bounds__(256)
void segsum_kernel(const float* __restrict__ x,
                   const int* __restrict__ sorted_rows,
                   const int* __restrict__ bin_start,
                   const int* __restrict__ counts_i,
                   float* __restrict__ embed_sum) {
    const int bid = blockIdx.x;
    const int l   = bid >> 11;
    const int e   = bid & 2047;
    const int tid = threadIdx.x;
    const int start = bin_start[l*EE + e];
    const int cnt   = counts_i[l*EE + e];
    const int* rows = sorted_rows + l*(NROWS/LL);

    float acc = 0.f;
    int i = 0;
    for (; i + 1 < cnt; i += 2) {
        int r0 = rows[start + i], r1 = rows[start + i + 1];
        acc += x[(size_t)r0*DD + tid] + x[(size_t)r1*DD + tid];
    }
    if (i < cnt) acc += x[(size_t)rows[start + i]*DD + tid];
    embed_sum[((size_t)l*EE + e)*DD + tid] = acc;
}

// ---------------------------------------------------------------------------
// Kernel 5: new_embed_avg + new_embed
// ---------------------------------------------------------------------------
__global__ void finalize_embed_kernel(const float* __restrict__ embed_avg,
                                      const float* __restrict__ embed_sum,
                                      const float* __restrict__ ncs,
                                      const float* __restrict__ n,
                                      float* __restrict__ nea_out,
                                      float* __restrict__ ne_out) {
    __shared__ float tile[32][33];
    const int l  = blockIdx.z;
    const int d0 = blockIdx.y * 32;
    const int e0 = blockIdx.x * 32;
    const int tx = threadIdx.x, ty = threadIdx.y;

    tile[ty][tx] = embed_sum[((size_t)l*EE + e0 + ty)*DD + d0 + tx];
    __syncthreads();
    const size_t idx = ((size_t)l*DD + d0 + ty)*EE + e0 + tx;
    float nea = 0.999f*embed_avg[idx] + 0.001f*tile[tx][ty];
    nea_out[idx] = nea;
    float nl = n[l];
    float c  = ncs[l*EE + e0 + tx];
    float cs = (c + 1e-5f) / (nl + 0.02048f) * nl;
    ne_out[idx] = nea / cs;
}

// ---------------------------------------------------------------------------
// Kernel 6: diff scale
// ---------------------------------------------------------------------------
__global__ void diff_scale_kernel(const float* __restrict__ diff_acc,
                                  float* __restrict__ diff_out) {
    *diff_out = (*diff_acc / (float)(BB*SS*DD)) * 0.25f;
}

// ---------------------------------------------------------------------------
extern "C" void kernel_launch(void* const* d_in, const int* in_sizes, int n_in,
                              void* d_out, int out_size, void* d_ws, size_t ws_size,
                              hipStream_t stream) {
    const float* x            = (const float*)d_in[0];
    const float* embed        = (const float*)d_in[1];
    const float* cluster_size = (const float*)d_in[2];
    const float* embed_avg    = (const float*)d_in[3];

    float* out      = (float*)d_out;
    float* diff_out = out + 33554432;
    int*   ids_out  = (int*)(out + 33554433);
    float* ne_out   = out + 33685505;
    float* ncs_out  = out + 37879809;
    float* nea_out  = out + 37896193;

    float* ws        = (float*)d_ws;
    float* embed_t   = ws;                          // LED floats
    float* embed_sum = ws + LED;                    // LED floats (fully written by segsum)
    int*   counts_i  = (int*)(ws + 2*(size_t)LED);  // LE ints   (zeroed)
    float* norms     = ws + 2*(size_t)LED + LE;     // LE floats (zeroed)
    float* diff_acc  = norms + LE;                  // 1 float   (zeroed)
    float* n_ws      = diff_acc + 1;                // LL floats
    int*   bin_start = (int*)(n_ws + LL);           // LE ints
    int*   cursor    = bin_start + LE;              // LE ints
    int*   sorted_rows = cursor + LE;               // NROWS ints
    __bf16* embfrag  = (__bf16*)(sorted_rows + NROWS + 16);  // LL*64*32*512 bf16 = 16 MB

    // zero: counts_i, norms, diff_acc (contiguous)
    hipMemsetAsync(counts_i, 0, (size_t)(2*LE + 1) * sizeof(float), stream);

    prep_transpose_kernel<<<dim3(EE/32, DD/32, LL), dim3(32, 32), 0, stream>>>(
        embed, embed_t, norms, embfrag);

    argmin_mfma<<<1024, 256, 0, stream>>>(x, embfrag, embed_t, norms, ids_out,
                                          counts_i, out, diff_acc);

    scan_kernel<<<LL, 256, 0, stream>>>(counts_i, cluster_size, bin_start, cursor,
                                        ncs_out, n_ws);

    scatter_idx_kernel<<<NROWS/256, 256, 0, stream>>>(ids_out, cursor, sorted_rows);

    segsum_kernel<<<LE, 256, 0, stream>>>(x, sorted_rows, bin_start, counts_i, embed_sum);

    finalize_embed_kernel<<<dim3(EE/32, DD/32, LL), dim3(32, 32), 0, stream>>>(
        embed_avg, embed_sum, ncs_out, n_ws, nea_out, ne_out);

    diff_scale_kernel<<<1, 1, 0, stream>>>(diff_acc, diff_out);
}

// Round 5
// 945.003 us; speedup vs baseline: 1.0682x; 1.0156x over previous
//
#include <hip/hip_runtime.h>

#define LL 8
#define BB 32
#define SS 512
#define DD 256
#define EE 2048
#define LED (LL*DD*EE)   // 4194304
#define LE  (LL*EE)      // 16384
#define NROWS (BB*LL*SS) // 131072
#define NSEG 33          // per-m staged segments: 16 ks x {hi,lo} + 1 norm seg

typedef __bf16 bf16x8 __attribute__((ext_vector_type(8)));
typedef float  f32x16 __attribute__((ext_vector_type(16)));

// ---------------------------------------------------------------------------
// Kernel 1 (merged): embed -> embed_t (transpose), norms (atomic partial),
// and MFMA A-fragment bf16 hi/lo segments — embed read exactly once.
// Frag layout per (l,m): segs 0..31 = ks 0..15 {hi,lo} interleaved; seg 32 =
// norm-fold seg (filled later by norm_seg_kernel once norms complete).
// ---------------------------------------------------------------------------
__global__ void prep_transpose_kernel(const float* __restrict__ embed,
                                      float* __restrict__ embed_t,
                                      float* __restrict__ norms,
                                      __bf16* __restrict__ frag) {
    __shared__ float tile[32][33];
    const int l  = blockIdx.z;
    const int d0 = blockIdx.y * 32;
    const int e0 = blockIdx.x * 32;
    const int tx = threadIdx.x, ty = threadIdx.y;

    float v = embed[((size_t)l*DD + d0 + ty)*EE + e0 + tx];
    tile[ty][tx] = v;
    __syncthreads();

    // transpose write
    embed_t[((size_t)l*EE + e0 + ty)*DD + d0 + tx] = tile[tx][ty];

    // frag hi/lo segments (coalesced: consecutive threads -> consecutive pos)
    const int t    = ty*32 + tx;
    const int ksl  = t >> 9;          // which of the 2 ks in this d-tile
    const int pos  = t & 511;         // position within segment
    const int lane = pos >> 3, j = pos & 7;
    const int klocal = (lane >> 5)*8 + j;
    const int e_loc  = lane & 31;
    float val = tile[ksl*16 + klocal][e_loc];
    __bf16 h = (__bf16)val;
    const int m  = blockIdx.x;
    const int ks = (d0 >> 4) + ksl;
    size_t segbase = (((size_t)(l*64 + m))*NSEG + 2*ks)*512 + pos;
    frag[segbase]       = h;
    frag[segbase + 512] = (__bf16)(val - (float)h);

    // norms partial
    if (ty == 0) {
        float s = 0.f;
        #pragma unroll
        for (int i = 0; i < 32; ++i) s += tile[i][tx]*tile[i][tx];
        atomicAdd(&norms[l*EE + e0 + tx], s);
    }
}

// ---------------------------------------------------------------------------
// Kernel 1c: fill norm-fold seg 32 per (l,m): lanes 0..31 hold hi/lo of
// -0.5*||e||^2 at k-slots 0,1; B-side (bh[16]) has ones at k=0,1 lanes<32.
// ---------------------------------------------------------------------------
__global__ void norm_seg_kernel(const float* __restrict__ norms,
                                __bf16* __restrict__ frag) {
    const int bid  = blockIdx.x;       // l*64 + m
    const int lane = threadIdx.x;
    bf16x8 v;
    #pragma unroll
    for (int j = 0; j < 8; ++j) v[j] = (__bf16)0.0f;
    if (lane < 32) {
        float nv = -0.5f * norms[(bid >> 6)*EE + (bid & 63)*32 + lane];
        __bf16 h = (__bf16)nv;
        v[0] = h;
        v[1] = (__bf16)(nv - (float)h);
    }
    *(bf16x8*)(frag + ((size_t)bid*NSEG + 32)*512 + lane*8) = v;
}

// ---------------------------------------------------------------------------
// Kernel 2: MFMA argmin. Diagnosis (r4 PMC): MFMA/LDS/VALU pipes additive
// (zero overlap, 8200 cyc/m vs 3900 floor). Fix: per-k sched_group_barrier
// forcing {2 ds_read | 3 MFMA | argmax-of-prev chunk} interleave, depth-1
// A-frag pipeline, double accumulator sets (A/B) so prev-m argmax VALU
// hides under cur-m MFMAs. Norm via r1-proven MFMA k-step. No setprio.
// + fused counts histogram + fused q-gather/out/diff.
// ---------------------------------------------------------------------------
__global__ __launch_bounds__(256, 2)
void argmin_mfma(const float* __restrict__ x,
                 const __bf16* __restrict__ frag,
                 const float* __restrict__ embed_t,
                 int* __restrict__ ids_out,
                 int* __restrict__ counts_i,
                 float* __restrict__ out,
                 float* __restrict__ diff_acc) {
    __shared__ __bf16 slots[2][NSEG*512];  // 2 x 33 KB double buffer

    const int tid  = threadIdx.x;
    const int wave = tid >> 6, lane = tid & 63;
    const int l    = blockIdx.x & 7;
    const int rb   = blockIdx.x >> 3;
    const int idx  = rb*4 + wave;
    const int b    = idx >> 4, st = idx & 15;
    const int rowtile = (b*LL + l)*16 + st;

    // x -> B fragments (hi/lo bf16 split); bh[16] = norm-fold ones vector
    bf16x8 bh[17], bl[16];
    {
        const float* xr = x + (size_t)(rowtile*32 + (lane & 31))*DD + (lane >> 5)*8;
        #pragma unroll
        for (int ks = 0; ks < 16; ++ks) {
            float4 v0 = *(const float4*)(xr + ks*16);
            float4 v1 = *(const float4*)(xr + ks*16 + 4);
            float f[8] = {v0.x, v0.y, v0.z, v0.w, v1.x, v1.y, v1.z, v1.w};
            #pragma unroll
            for (int j = 0; j < 8; ++j) {
                __bf16 h = (__bf16)f[j];
                bh[ks][j] = h;
                bl[ks][j] = (__bf16)(f[j] - (float)h);
            }
        }
        #pragma unroll
        for (int j = 0; j < 8; ++j) bh[16][j] = (__bf16)0.0f;
        if (lane < 32) { bh[16][0] = (__bf16)1.0f; bh[16][1] = (__bf16)1.0f; }
    }

    const __bf16* fl = frag + (size_t)l*64*NSEG*512;

    // stage full m (33 segs) into buf; 8-9 global_load_lds per wave
    auto stage = [&](int m, int buf) {
        const __bf16* src = fl + (size_t)m*NSEG*512 + lane*8;
        __bf16* dst = &slots[buf][0];
        for (int i = wave; i < NSEG; i += 4) {
            __builtin_amdgcn_global_load_lds(
                (const __attribute__((address_space(1))) void*)(src + i*512),
                (__attribute__((address_space(3))) void*)(dst + i*512), 16, 0, 0);
        }
    };

    float maxv = -1e30f;
    int   maxi = 0;

    // one m-step: compute (Pc,Qc) for tile m while argmax-reducing (Pp,Qp)
    // of tile m-1, interleaved per-k via sched_group_barrier.
    auto step = [&](int m, f32x16& Pc, f32x16& Qc, f32x16& Pp, f32x16& Qp) {
        #pragma unroll
        for (int i = 0; i < 16; ++i) { Pc[i] = 0.0f; Qc[i] = 0.0f; }
        if (m < 63) stage(m + 1, (m & 1) ^ 1);
        const __bf16* sA = &slots[m & 1][0];
        const int pbase = (m - 1)*32 + 4*(lane >> 5);

        bf16x8 ah = *(const bf16x8*)(sA + 0*512 + lane*8);
        bf16x8 al = *(const bf16x8*)(sA + 1*512 + lane*8);
        #pragma unroll
        for (int k = 0; k < 16; ++k) {
            bf16x8 nh, nl;
            if (k < 15) {
                nh = *(const bf16x8*)(sA + (2*k + 2)*512 + lane*8);
                nl = *(const bf16x8*)(sA + (2*k + 3)*512 + lane*8);
            } else {
                nh = *(const bf16x8*)(sA + 32*512 + lane*8);   // norm seg
                nl = nh;
            }
            Pc = __builtin_amdgcn_mfma_f32_32x32x16_bf16(ah, bh[k], Pc, 0, 0, 0);
            Qc = __builtin_amdgcn_mfma_f32_32x32x16_bf16(ah, bl[k], Qc, 0, 0, 0);
            Pc = __builtin_amdgcn_mfma_f32_32x32x16_bf16(al, bh[k], Pc, 0, 0, 0);
            {   // argmax chunk: entry k of previous m (e ascending in k)
                float v = Pp[k] + Qp[k];
                int e = pbase + (k & 3) + 8*(k >> 2);
                if (v > maxv) { maxv = v; maxi = e; }
            }
            ah = nh; al = nl;
            if (k < 15) __builtin_amdgcn_sched_group_barrier(0x100, 2, 0);
            else        __builtin_amdgcn_sched_group_barrier(0x100, 1, 0);
            __builtin_amdgcn_sched_group_barrier(0x008, 3, 0);
            __builtin_amdgcn_sched_group_barrier(0x002, 8, 0);
        }
        // norm fold: D += normseg * ones(k=0,1)
        Pc = __builtin_amdgcn_mfma_f32_32x32x16_bf16(ah, bh[16], Pc, 0, 0, 0);
        __syncthreads();   // next buffer staged; all waves done reading this one
    };

    f32x16 PA, QA, PB, QB;
    #pragma unroll
    for (int i = 0; i < 16; ++i) { PB[i] = -1e30f; QB[i] = -1e30f; }  // m=-1 sentinel

    stage(0, 0);
    __syncthreads();

    #pragma unroll 1
    for (int t = 0; t < 32; ++t) {
        step(2*t,     PA, QA, PB, QB);
        step(2*t + 1, PB, QB, PA, QA);
    }
    // drain: argmax of m=63 (held in PB,QB)
    {
        const int pbase = 63*32 + 4*(lane >> 5);
        #pragma unroll
        for (int k = 0; k < 16; ++k) {
            float v = PB[k] + QB[k];
            int e = pbase + (k & 3) + 8*(k >> 2);
            if (v > maxv) { maxv = v; maxi = e; }
        }
    }

    float ov = __shfl_xor(maxv, 32, 64);
    int   oi = __shfl_xor(maxi, 32, 64);
    if (ov > maxv || (ov == maxv && oi < maxi)) { maxv = ov; maxi = oi; }
    if (lane < 32) {
        ids_out[(size_t)rowtile*32 + lane] = maxi;
        atomicAdd(&counts_i[l*EE + maxi], 1);
    }

    // ---- fused gather q -> out (+ diff partial for l == L-1) ----
    const float4* et4  = (const float4*)embed_t;
    const float4* x4   = (const float4*)x;
    float4*       out4 = (float4*)out;
    float sq = 0.f;
    #pragma unroll 4
    for (int r = 0; r < 32; ++r) {
        int id = __shfl(maxi, r);   // all 64 lanes hold row r's result after combine
        float4 qv = et4[((size_t)l*EE + id)*64 + lane];
        size_t o = ((size_t)rowtile*32 + r)*64 + lane;
        out4[o] = qv;
        if (l == LL - 1) {
            float4 xv = x4[o];
            float dx = qv.x - xv.x, dy = qv.y - xv.y, dz = qv.z - xv.z, dw = qv.w - xv.w;
            sq += dx*dx + dy*dy + dz*dz + dw*dw;
        }
    }
    if (l == LL - 1) {
        #pragma unroll
        for (int off = 32; off; off >>= 1) sq += __shfl_down(sq, off);
        if (lane == 0) atomicAdd(diff_acc, sq);
    }
}

// ---------------------------------------------------------------------------
// Kernel 2b: per-l exclusive scan of counts -> bin_start, cursor
//            + fused new_cluster_size & per-l sum n
// ---------------------------------------------------------------------------
__global__ __launch_bounds__(256)
void scan_kernel(const int* __restrict__ counts_i,
                 const float* __restrict__ cs_in,
                 int* __restrict__ bin_start,
                 int* __restrict__ cursor,
                 float* __restrict__ ncs_out,
                 float* __restrict__ n_out) {
    __shared__ int part[256];
    __shared__ float red[4];
    const int l = blockIdx.x, tid = threadIdx.x;
    const int base = l*EE + tid*8;
    int local[8], tsum = 0;
    float fsum = 0.f;
    #pragma unroll
    for (int j = 0; j < 8; ++j) {
        local[j] = counts_i[base + j];
        tsum += local[j];
        float v = 0.999f*cs_in[base + j] + 0.001f*(float)local[j];
        ncs_out[base + j] = v;
        fsum += v;
    }
    part[tid] = tsum;
    __syncthreads();
    for (int off = 1; off < 256; off <<= 1) {
        int v = (tid >= off) ? part[tid - off] : 0;
        __syncthreads();
        part[tid] += v;
        __syncthreads();
    }
    int run = part[tid] - tsum;
    #pragma unroll
    for (int j = 0; j < 8; ++j) {
        bin_start[base + j] = run;
        cursor[base + j]    = run;
        run += local[j];
    }
    #pragma unroll
    for (int off = 32; off; off >>= 1) fsum += __shfl_down(fsum, off);
    if ((tid & 63) == 0) red[tid >> 6] = fsum;
    __syncthreads();
    if (tid == 0) n_out[l] = red[0] + red[1] + red[2] + red[3];
}

// ---------------------------------------------------------------------------
// Kernel 2c: scatter row indices into per-l sorted order
// ---------------------------------------------------------------------------
__global__ __launch_bounds__(256)
void scatter_idx_kernel(const int* __restrict__ ids,
                        int* __restrict__ cursor,
                        int* __restrict__ sorted_rows) {
    const int r = blockIdx.x*256 + threadIdx.x;
    const int l = (r >> 9) & 7;
    const int e = ids[r];
    int pos = atomicAdd(&cursor[l*EE + e], 1);
    sorted_rows[l*(NROWS/LL) + pos] = r;
}

// ---------------------------------------------------------------------------
// Kernel 2d: segmented sum — one block per (l,e), threads = d
// ---------------------------------------------------------------------------
__global__ __launch_bounds__(256)
void segsum_kernel(const float* __restrict__ x,
                   const int* __restrict__ sorted_rows,
                   const int* __restrict__ bin_start,
                   const int* __restrict__ counts_i,
                   float* __restrict__ embed_sum) {
    const int bid = blockIdx.x;
    const int l   = bid >> 11;
    const int e   = bid & 2047;
    const int tid = threadIdx.x;
    const int start = bin_start[l*EE + e];
    const int cnt   = counts_i[l*EE + e];
    const int* rows = sorted_rows + l*(NROWS/LL);

    float acc = 0.f;
    int i = 0;
    for (; i + 1 < cnt; i += 2) {
        int r0 = rows[start + i], r1 = rows[start + i + 1];
        acc += x[(size_t)r0*DD + tid] + x[(size_t)r1*DD + tid];
    }
    if (i < cnt) acc += x[(size_t)rows[start + i]*DD + tid];
    embed_sum[((size_t)l*EE + e)*DD + tid] = acc;
}

// ---------------------------------------------------------------------------
// Kernel 5: new_embed_avg + new_embed
// ---------------------------------------------------------------------------
__global__ void finalize_embed_kernel(const float* __restrict__ embed_avg,
                                      const float* __restrict__ embed_sum,
                                      const float* __restrict__ ncs,
                                      const float* __restrict__ n,
                                      float* __restrict__ nea_out,
                                      float* __restrict__ ne_out) {
    __shared__ float tile[32][33];
    const int l  = blockIdx.z;
    const int d0 = blockIdx.y * 32;
    const int e0 = blockIdx.x * 32;
    const int tx = threadIdx.x, ty = threadIdx.y;

    tile[ty][tx] = embed_sum[((size_t)l*EE + e0 + ty)*DD + d0 + tx];
    __syncthreads();
    const size_t idx = ((size_t)l*DD + d0 + ty)*EE + e0 + tx;
    float nea = 0.999f*embed_avg[idx] + 0.001f*tile[tx][ty];
    nea_out[idx] = nea;
    float nl = n[l];
    float c  = ncs[l*EE + e0 + tx];
    float cs = (c + 1e-5f) / (nl + 0.02048f) * nl;
    ne_out[idx] = nea / cs;
}

// ---------------------------------------------------------------------------
// Kernel 6: diff scale
// ---------------------------------------------------------------------------
__global__ void diff_scale_kernel(const float* __restrict__ diff_acc,
                                  float* __restrict__ diff_out) {
    *diff_out = (*diff_acc / (float)(BB*SS*DD)) * 0.25f;
}

// ---------------------------------------------------------------------------
extern "C" void kernel_launch(void* const* d_in, const int* in_sizes, int n_in,
                              void* d_out, int out_size, void* d_ws, size_t ws_size,
                              hipStream_t stream) {
    const float* x            = (const float*)d_in[0];
    const float* embed        = (const float*)d_in[1];
    const float* cluster_size = (const float*)d_in[2];
    const float* embed_avg    = (const float*)d_in[3];

    float* out      = (float*)d_out;
    float* diff_out = out + 33554432;
    int*   ids_out  = (int*)(out + 33554433);
    float* ne_out   = out + 33685505;
    float* ncs_out  = out + 37879809;
    float* nea_out  = out + 37896193;

    float* ws        = (float*)d_ws;
    float* embed_t   = ws;                          // LED floats
    float* embed_sum = ws + LED;                    // LED floats (fully written by segsum)
    int*   counts_i  = (int*)(ws + 2*(size_t)LED);  // LE ints   (zeroed)
    float* norms     = ws + 2*(size_t)LED + LE;     // LE floats (zeroed)
    float* diff_acc  = norms + LE;                  // 1 float   (zeroed)
    float* n_ws      = diff_acc + 1;                // LL floats
    int*   bin_start = (int*)(n_ws + LL);           // LE ints
    int*   cursor    = bin_start + LE;              // LE ints
    int*   sorted_rows = cursor + LE;               // NROWS ints
    __bf16* embfrag  = (__bf16*)(sorted_rows + NROWS + 16);  // LL*64*33*512 bf16

    // zero: counts_i, norms, diff_acc (contiguous)
    hipMemsetAsync(counts_i, 0, (size_t)(2*LE + 1) * sizeof(float), stream);

    prep_transpose_kernel<<<dim3(EE/32, DD/32, LL), dim3(32, 32), 0, stream>>>(
        embed, embed_t, norms, embfrag);

    norm_seg_kernel<<<LL*64, 64, 0, stream>>>(norms, embfrag);

    argmin_mfma<<<1024, 256, 0, stream>>>(x, embfrag, embed_t, ids_out,
                                          counts_i, out, diff_acc);

    scan_kernel<<<LL, 256, 0, stream>>>(counts_i, cluster_size, bin_start, cursor,
                                        ncs_out, n_ws);

    scatter_idx_kernel<<<NROWS/256, 256, 0, stream>>>(ids_out, cursor, sorted_rows);

    segsum_kernel<<<LE, 256, 0, stream>>>(x, sorted_rows, bin_start, counts_i, embed_sum);

    finalize_embed_kernel<<<dim3(EE/32, DD/32, LL), dim3(32, 32), 0, stream>>>(
        embed_avg, embed_sum, ncs_out, n_ws, nea_out, ne_out);

    diff_scale_kernel<<<1, 1, 0, stream>>>(diff_acc, diff_out);
}